// Round 8
// baseline (56.985 us; speedup 1.0000x reference)
//
#include <hip/hip_runtime.h>
#include <hip/hip_cooperative_groups.h>
#include <stdint.h>

#define TILE_LEN 16
#define KMAX 64
#define IMGW 512
#define IMGH 512
#define TXN 32
#define TYN 32
#define TPB 4                    // tiles per block (along x, same tile-row)
#define NBLK 256                 // = TXN*TYN/TPB; also == CU count (co-resident)
#define BT 1024                  // threads per block
#define NBLKA_MAX 64             // max phase-A blocks (N <= 65536)
#define SEGCAP 384               // per-(row, A-block) segment cap (mean ~58)
#define CCAP 256                 // per-tile candidate cap (mean ~46)

namespace cg = cooperative_groups;

// ---------------------------------------------------------------------------
// One cooperative kernel, two phases split by grid.sync():
//  A) blocks 0..nblkA-1 (1024 gaussians each): exact _rn radius chain ONCE
//     per gaussian -> sA[i]=(px,py,r,opac); exact y-overlap test per tile-row;
//     append idx into PRIVATE segment seg[row][blk] via per-block LDS counter
//     (plain global stores, no global atomics, no zeroing needed -- counts
//     fully overwritten every launch -> graph-replay safe).
//  B) block b owns tiles (txb..txb+3, ty): prefix its row's nblkA segment
//     counts, scan ~920 row candidates (sA only, no radius recompute), exact
//     x-test, per-tile LDS-atomic append; stable depth sort via unique keys
//     (depth_bits<<32)|idx; gather params (1/det precomputed); blend; store.
// Selection arithmetic byte-identical to the R4/R6 passing kernels; segment
// append order nondeterminism is normalized by the unique-key rank sort.
// ---------------------------------------------------------------------------
__global__ __launch_bounds__(BT) void fused_coop(
    const float* __restrict__ pos2d, const float* __restrict__ cov2d,
    const float* __restrict__ opac,  const float* __restrict__ color,
    const float* __restrict__ depth, float* __restrict__ out,
    float4* __restrict__ sA, int* __restrict__ blkcnt, int* __restrict__ seg,
    int nblkA, int N)
{
    __shared__ int      aw_cnt[TYN];
    __shared__ int      s_segbase[NBLKA_MAX + 1];
    __shared__ int      s_cnt[TPB];
    __shared__ int      s_cand[TPB][CCAP];
    __shared__ uint64_t s_keys[TPB][CCAP];
    __shared__ int      s_sel[TPB][KMAX];
    __shared__ float4   pA[TPB][KMAX], pB[TPB][KMAX], pC[TPB][KMAX];

    const int t   = threadIdx.x;
    const int blk = blockIdx.x;

    if (t < TPB) s_cnt[t] = 0;

    // ---- Phase A: per-gaussian prep + segmented row binning
    if (blk < nblkA) {
        if (t < TYN) aw_cnt[t] = 0;
        __syncthreads();

        const int i = blk * BT + t;
        if (i < N) {
            const float2 p  = ((const float2*)pos2d)[i];
            const float4 cv = ((const float4*)cov2d)[i];   // [a, b, b, c]
            const float a = cv.x, b = cv.y, c = cv.w;

            // radius chain with _rn intrinsics: forbids fma contraction
            // (selection-critical, feeds exact bbox-overlap compares)
            const float trace = __fadd_rn(a, c);
            const float det   = __fsub_rn(__fmul_rn(a, c), __fmul_rn(b, b));
            float arg = __fsub_rn(__fmul_rn(trace, trace), __fmul_rn(4.0f, det));
            arg = fmaxf(arg, 0.0f);
            const float t1 = __fmul_rn(0.5f, trace);
            const float t2 = __fmul_rn(0.5f, sqrtf(arg));
            const float lam = fmaxf(__fsub_rn(t1, t2), __fadd_rn(t1, t2));
            const float r = __fmul_rn(3.0f, sqrtf(lam));

            sA[i] = make_float4(p.x, p.y, r, opac[i]);

            // conservative row range (+/-1 tile margin), exact test per row
            const int ty0 = max((int)floorf((p.y - r) * 0.0625f) - 1, 0);
            const int ty1 = min((int)floorf((p.y + r) * 0.0625f) + 1, TYN - 1);
            const float yp = __fadd_rn(p.y, r);
            const float ym = __fsub_rn(p.y, r);
            for (int ty = ty0; ty <= ty1; ++ty) {
                const float Tf = (float)(ty * TILE_LEN);
                if ((yp > Tf) && (ym < Tf + (float)TILE_LEN)) {
                    const int pos = atomicAdd(&aw_cnt[ty], 1);   // LDS atomic
                    if (pos < SEGCAP)
                        seg[(ty * NBLKA_MAX + blk) * SEGCAP + pos] = i;
                }
            }
        }
        __syncthreads();
        if (t < TYN) blkcnt[blk * TYN + t] = min(aw_cnt[t], SEGCAP);
    }

    cg::this_grid().sync();   // device-scope fence: sA/blkcnt/seg visible

    // ---- Phase B: per-4-tile-group selection + sort + blend
    const int ty  = blk & (TYN - 1);
    const int txb = (blk >> 5) * TPB;
    const float Tf  = (float)(ty * TILE_LEN);
    const float Lf0 = (float)(txb * TILE_LEN);

    // segment prefix for this row (parallel load, tiny serial LDS scan)
    if (t < nblkA) s_segbase[t + 1] = blkcnt[t * TYN + ty];
    if (t == 0) s_segbase[0] = 0;
    __syncthreads();
    if (t == 0) {
        int s = 0;
        for (int b = 0; b < nblkA; ++b) { s += s_segbase[b + 1]; s_segbase[b + 1] = s; }
    }
    __syncthreads();
    const int C = s_segbase[nblkA];

    // scan row candidates: exact x-overlap test, per-tile append
    for (int k = t; k < C; k += BT) {
        int b = 0;
        while (s_segbase[b + 1] <= k) ++b;
        const int idx = seg[(ty * NBLKA_MAX + b) * SEGCAP + (k - s_segbase[b])];
        const float4 A = sA[idx];
        const float xp = __fadd_rn(A.x, A.z);
        const float xm = __fsub_rn(A.x, A.z);
#pragma unroll
        for (int g = 0; g < TPB; ++g) {
            const float Lf = Lf0 + (float)(g * TILE_LEN);
            if ((xp > Lf) && (xm < Lf + (float)TILE_LEN)) {
                const int pos = atomicAdd(&s_cnt[g], 1);   // LDS atomic, ~46/tile
                if (pos < CCAP) s_cand[g][pos] = idx;
            }
        }
    }
    __syncthreads();

    // ---- stable depth sort per tile (rank sort, unique keys)
    const int g8 = t >> 8;    // tile group 0..3 (256 threads each)
    const int m  = t & 255;
    const int M  = min(s_cnt[g8], CCAP);

    uint64_t mykey = 0;
    int myidx = -1;
    if (m < M) {
        myidx = s_cand[g8][m];
        mykey = ((uint64_t)__float_as_uint(depth[myidx]) << 32) | (uint32_t)myidx;
        s_keys[g8][m] = mykey;
    }
    __syncthreads();

    if (m < M) {
        int rank = 0;
        for (int j = 0; j < M; ++j)
            rank += (s_keys[g8][j] < mykey) ? 1 : 0;
        if (rank < KMAX) s_sel[g8][rank] = myidx;   // unique ranks
    }
    __syncthreads();

    // ---- gather selected gaussians' params into LDS
    if (t < TPB * KMAX) {
        const int g = t >> 6, k = t & 63;
        const int K = min(min(s_cnt[g], CCAP), KMAX);
        if (k < K) {
            const int idx = s_sel[g][k];
            const float4 A  = sA[idx];                       // px, py, r, opac
            const float4 cv = ((const float4*)cov2d)[idx];
            const float det = __fsub_rn(__fmul_rn(cv.x, cv.w), __fmul_rn(cv.y, cv.y));
            pA[g][k] = make_float4(A.x, A.y, 0.0f, A.w);
            pB[g][k] = make_float4(cv.x, cv.y, cv.w, 1.0f / det);
            pC[g][k] = make_float4(color[3 * idx], color[3 * idx + 1],
                                   color[3 * idx + 2], 0.0f);
        }
    }
    __syncthreads();

    // ---- per-pixel front-to-back blend (all 1024 threads)
    const int pix = t & 255;
    const int pi = pix >> 4;       // x offset in tile
    const int pj = pix & 15;       // y offset in tile
    const int K = min(M, KMAX);
    const float x = Lf0 + (float)(g8 * TILE_LEN + pi);
    const float y = Tf + (float)pj;

    float Tacc = 1.0f, cr = 0.0f, cg_ = 0.0f, cb = 0.0f;
    for (int k = 0; k < K; ++k) {
        const float4 A  = pA[g8][k];
        const float4 B  = pB[g8][k];
        const float4 Cc = pC[g8][k];
        const float dx = x - A.x;
        const float dy = y - A.y;
        const float quad = (B.z * dx * dx - 2.0f * B.y * dx * dy + B.x * dy * dy) * B.w;
        const float prob = __expf(-0.5f * quad);
        const float alpha = fminf(fmaxf(A.w * prob, 0.01f), 0.99f);
        const float wgt = alpha * Tacc;
        cr  = fmaf(wgt, Cc.x, cr);
        cg_ = fmaf(wgt, Cc.y, cg_);
        cb  = fmaf(wgt, Cc.z, cb);
        Tacc *= (1.0f - alpha);
    }

    const int X = (txb + g8) * TILE_LEN + pi;
    const int Y = ty * TILE_LEN + pj;
    float* o = out + ((size_t)X * IMGW + (size_t)Y) * 3;
    o[0] = cr;
    o[1] = cg_;
    o[2] = cb;
}

// ---------------------------------------------------------------------------
extern "C" void kernel_launch(void* const* d_in, const int* in_sizes, int n_in,
                              void* d_out, int out_size, void* d_ws, size_t ws_size,
                              hipStream_t stream)
{
    const float* pos2d = (const float*)d_in[0];
    const float* cov2d = (const float*)d_in[1];
    const float* opac  = (const float*)d_in[2];
    const float* color = (const float*)d_in[3];
    const float* depth = (const float*)d_in[4];
    float* out = (float*)d_out;

    const int N = in_sizes[2];  // opacity count == N_GAUSS
    int nblkA = (N + BT - 1) / BT;
    if (nblkA > NBLKA_MAX) nblkA = NBLKA_MAX;

    // workspace layout (fully overwritten each launch; no zeroing needed):
    //   sA:     float4[65536]                      (px, py, r, opac)
    //   blkcnt: int[NBLKA_MAX * TYN]
    //   seg:    int[TYN * NBLKA_MAX * SEGCAP]
    float4* sA   = (float4*)d_ws;
    int* blkcnt  = (int*)(sA + 65536);
    int* seg     = blkcnt + NBLKA_MAX * TYN;

    void* args[] = {
        (void*)&pos2d, (void*)&cov2d, (void*)&opac, (void*)&color,
        (void*)&depth, (void*)&out, (void*)&sA, (void*)&blkcnt,
        (void*)&seg, (void*)&nblkA, (void*)&N
    };
    hipLaunchCooperativeKernel((void*)fused_coop, dim3(NBLK), dim3(BT),
                               args, 0, stream);
}

// Round 9
// 30.052 us; speedup vs baseline: 1.8962x; 1.8962x over previous
//
#include <hip/hip_runtime.h>
#include <stdint.h>

#define TILE_LEN 16
#define KMAX 64
#define IMGW 512
#define IMGH 512
#define TXN 32
#define TYN 32
#define TPB 4                    // tiles per block (along x, same tile-row)
#define NBLK ((TXN * TYN) / TPB) // 256 blocks
#define BT 1024                  // threads per block
#define NWAVE (BT / 64)          // 16 waves
#define WCAP 96                  // per-wave survivor cap (mean ~9, huge margin)
#define SURVCAP 512              // dense survivor cap (mean ~147)
#define CCAP 256                 // per-tile candidate cap (mean ~46)

// ---------------------------------------------------------------------------
// Single fused kernel (R6 structure -- best measured). Block b owns tiles
// (txb..txb+3, ty), ty = b & 31.
//  1a) conservative sqrt-free prefilter (r <= 3*sqrt(trace) for PSD cov;
//      2% slack vs rounding). Survivors compacted into PER-WAVE private LDS
//      segments (no cross-wave atomics in the hot loop).
//  1a') prefix over wave counts + wave-parallel merge into dense list
//      (order nondeterministic -- made irrelevant by the unique-key sort).
//  1b) exact _rn radius chain + exact y/x overlap tests on survivors only.
//      Byte-identical selection arithmetic to the passing kernels.
//  2)  per-tile stable depth sort: rank sort over unique 64-bit keys
//      (depth_bits << 32) | idx  (depth >= 0 -> bits order-isomorphic).
//  3)  gather params with strength-reduced quad coeffs
//      (qa,qb,qc) = (-c/2det, b/det, -a/2det); blend with wave-uniform
//      transmittance early-out (error < 1.5e-3 << threshold); store.
// ---------------------------------------------------------------------------
__global__ __launch_bounds__(BT) void fused_splat(
    const float* __restrict__ pos2d, const float* __restrict__ cov2d,
    const float* __restrict__ opac,  const float* __restrict__ color,
    const float* __restrict__ depth, float* __restrict__ out, int N)
{
    __shared__ int      s_seg[NWAVE * WCAP];
    __shared__ int      s_wsc[NWAVE];
    __shared__ int      s_wbase[NWAVE + 1];
    __shared__ int      s_surv[SURVCAP];
    __shared__ int      s_cnt[TPB];
    __shared__ int      s_cand[TPB][CCAP];
    __shared__ uint64_t s_keys[TPB][CCAP];
    __shared__ int      s_sel[TPB][KMAX];
    __shared__ float4   pA[TPB][KMAX], pB[TPB][KMAX], pC[TPB][KMAX];

    const int t    = threadIdx.x;
    const int lane = t & 63;
    const int w    = t >> 6;
    const int ty   = blockIdx.x & (TYN - 1);
    const int txb  = (blockIdx.x >> 5) * TPB;
    const float Tf  = (float)(ty * TILE_LEN);
    const float Lf0 = (float)(txb * TILE_LEN);
    const float Yc  = Tf + 8.0f;     // row band center
    const float Xc  = Lf0 + 32.0f;   // 4-tile band center

    if (t < TPB) s_cnt[t] = 0;
    __syncthreads();

    const float2* __restrict__ posv = (const float2*)pos2d;
    const float4* __restrict__ covv = (const float4*)cov2d;
    const unsigned long long below = (1ull << lane) - 1ull;

    // ---- Phase 1a: prefilter scan, per-wave private compaction, unroll x2
    int wcnt = 0;
    for (int base = 0; base < N; base += 2 * BT) {
        const int i0 = base + t;
        const int i1 = base + BT + t;
        bool sv0 = false, sv1 = false;
        if (i0 < N) {
            const float2 p  = posv[i0];
            const float4 cv = covv[i0];
            const float rb2 = 9.2f * (cv.x + cv.w);
            const float sy = fabsf(p.y - Yc) - 8.0f;
            const float sx = fabsf(p.x - Xc) - 32.0f;
            sv0 = !(((sy > 0.0f) && (sy * sy > rb2)) ||
                    ((sx > 0.0f) && (sx * sx > rb2)));
        }
        if (i1 < N) {
            const float2 p  = posv[i1];
            const float4 cv = covv[i1];
            const float rb2 = 9.2f * (cv.x + cv.w);
            const float sy = fabsf(p.y - Yc) - 8.0f;
            const float sx = fabsf(p.x - Xc) - 32.0f;
            sv1 = !(((sy > 0.0f) && (sy * sy > rb2)) ||
                    ((sx > 0.0f) && (sx * sx > rb2)));
        }
        const unsigned long long m0 = __ballot(sv0);
        if (sv0) {
            const int pos = wcnt + __popcll(m0 & below);
            if (pos < WCAP) s_seg[w * WCAP + pos] = i0;
        }
        wcnt += __popcll(m0);
        const unsigned long long m1 = __ballot(sv1);
        if (sv1) {
            const int pos = wcnt + __popcll(m1 & below);
            if (pos < WCAP) s_seg[w * WCAP + pos] = i1;
        }
        wcnt += __popcll(m1);
    }
    if (lane == 0) s_wsc[w] = min(wcnt, WCAP);
    __syncthreads();

    // ---- Phase 1a': prefix over wave counts + wave-parallel dense merge
    if (t == 0) {
        int s = 0;
        for (int v = 0; v < NWAVE; ++v) { s_wbase[v] = s; s += s_wsc[v]; }
        s_wbase[NWAVE] = s;
    }
    __syncthreads();
    const int S = min(s_wbase[NWAVE], SURVCAP);
    {
        const int cnt = s_wsc[w];
        const int b0 = s_wbase[w];
        for (int k = lane; k < cnt; k += 64) {
            const int dst = b0 + k;
            if (dst < SURVCAP) s_surv[dst] = s_seg[w * WCAP + k];
        }
    }
    __syncthreads();

    // ---- Phase 1b: exact selection tests on survivors (dense)
    for (int k = t; k < S; k += BT) {
        const int i = s_surv[k];
        const float2 p  = posv[i];
        const float4 cv = covv[i];
        const float a = cv.x, b = cv.y, c = cv.w;

        // radius chain with _rn intrinsics: forbids fma contraction
        // (selection-critical, feeds exact bbox-overlap compares)
        const float trace = __fadd_rn(a, c);
        const float det   = __fsub_rn(__fmul_rn(a, c), __fmul_rn(b, b));
        float arg = __fsub_rn(__fmul_rn(trace, trace), __fmul_rn(4.0f, det));
        arg = fmaxf(arg, 0.0f);
        const float t1 = __fmul_rn(0.5f, trace);
        const float t2 = __fmul_rn(0.5f, sqrtf(arg));
        const float lam = fmaxf(__fsub_rn(t1, t2), __fadd_rn(t1, t2));
        const float r = __fmul_rn(3.0f, sqrtf(lam));

        const float yp = __fadd_rn(p.y, r);
        const float ym = __fsub_rn(p.y, r);
        if ((yp > Tf) && (ym < Tf + (float)TILE_LEN)) {
            const float xp = __fadd_rn(p.x, r);
            const float xm = __fsub_rn(p.x, r);
#pragma unroll
            for (int g = 0; g < TPB; ++g) {
                const float Lf = Lf0 + (float)(g * TILE_LEN);
                if ((xp > Lf) && (xm < Lf + (float)TILE_LEN)) {
                    const int pos = atomicAdd(&s_cnt[g], 1);   // LDS atomic, ~150 total
                    if (pos < CCAP) s_cand[g][pos] = i;
                }
            }
        }
    }
    __syncthreads();

    // ---- Phase 2: per-tile stable depth sort (rank sort, unique keys)
    const int g8 = t >> 8;    // tile group 0..3 (256 threads each)
    const int m  = t & 255;
    const int M  = min(s_cnt[g8], CCAP);

    uint64_t mykey = 0;
    int myidx = -1;
    if (m < M) {
        myidx = s_cand[g8][m];
        mykey = ((uint64_t)__float_as_uint(depth[myidx]) << 32) | (uint32_t)myidx;
        s_keys[g8][m] = mykey;
    }
    __syncthreads();

    if (m < M) {
        int rank = 0;
        for (int j = 0; j < M; ++j)
            rank += (s_keys[g8][j] < mykey) ? 1 : 0;
        if (rank < KMAX) s_sel[g8][rank] = myidx;   // unique ranks
    }
    __syncthreads();

    // ---- Phase 3a: gather params; strength-reduced quad coefficients
    if (t < TPB * KMAX) {
        const int g = t >> 6, k = t & 63;
        const int K = min(min(s_cnt[g], CCAP), KMAX);
        if (k < K) {
            const int idx = s_sel[g][k];
            const float2 p  = posv[idx];
            const float4 cv = covv[idx];
            const float det = __fsub_rn(__fmul_rn(cv.x, cv.w), __fmul_rn(cv.y, cv.y));
            const float invdet = 1.0f / det;
            pA[g][k] = make_float4(p.x, p.y, 0.0f, opac[idx]);
            // -0.5*quad = qa*dx^2 + qb*dx*dy + qc*dy^2
            pB[g][k] = make_float4(-0.5f * cv.w * invdet,  cv.y * invdet,
                                   -0.5f * cv.x * invdet, 0.0f);
            pC[g][k] = make_float4(color[3 * idx], color[3 * idx + 1],
                                   color[3 * idx + 2], 0.0f);
        }
    }
    __syncthreads();

    // ---- Phase 3b: per-pixel front-to-back blend (all 1024 threads)
    const int pix = t & 255;
    const int pi = pix >> 4;       // x offset in tile
    const int pj = pix & 15;       // y offset in tile
    const int K = min(M, KMAX);
    const float x = Lf0 + (float)(g8 * TILE_LEN + pi);
    const float y = Tf + (float)pj;

    float Tacc = 1.0f, cr = 0.0f, cg = 0.0f, cb = 0.0f;
    for (int k = 0; k < K; ++k) {
        const float4 A  = pA[g8][k];
        const float4 B  = pB[g8][k];
        const float4 Cc = pC[g8][k];
        const float dx = x - A.x;
        const float dy = y - A.y;
        const float arg = fmaf(dx, fmaf(B.x, dx, B.y * dy), B.z * dy * dy);
        const float prob = __expf(arg);
        const float alpha = fminf(fmaxf(A.w * prob, 0.01f), 0.99f);
        const float wgt = alpha * Tacc;
        cr = fmaf(wgt, Cc.x, cr);
        cg = fmaf(wgt, Cc.y, cg);
        cb = fmaf(wgt, Cc.z, cb);
        Tacc *= (1.0f - alpha);
        // wave-uniform early-out: tail error <= Tacc < 1.5e-3 per channel
        if (__all(Tacc < 1.5e-3f)) break;
    }

    const int X = (txb + g8) * TILE_LEN + pi;
    const int Y = ty * TILE_LEN + pj;
    float* o = out + ((size_t)X * IMGW + (size_t)Y) * 3;
    o[0] = cr;
    o[1] = cg;
    o[2] = cb;
}

// ---------------------------------------------------------------------------
extern "C" void kernel_launch(void* const* d_in, const int* in_sizes, int n_in,
                              void* d_out, int out_size, void* d_ws, size_t ws_size,
                              hipStream_t stream)
{
    const float* pos2d = (const float*)d_in[0];
    const float* cov2d = (const float*)d_in[1];
    const float* opac  = (const float*)d_in[2];
    const float* color = (const float*)d_in[3];
    const float* depth = (const float*)d_in[4];
    float* out = (float*)d_out;

    const int N = in_sizes[2];  // opacity count == N_GAUSS

    fused_splat<<<NBLK, BT, 0, stream>>>(pos2d, cov2d, opac, color, depth, out, N);
}

// Round 10
// 28.397 us; speedup vs baseline: 2.0067x; 1.0583x over previous
//
#include <hip/hip_runtime.h>
#include <stdint.h>

#define TILE_LEN 16
#define KMAX 64
#define IMGW 512
#define IMGH 512
#define TXN 32
#define TYN 32
#define TPB 4                    // tiles per block (along x, same tile-row)
#define NBLK ((TXN * TYN) / TPB) // 256 blocks
#define BT 1024                  // threads per block
#define CCAP 256                 // per-tile candidate cap (mean ~46)
#define SURVCAP 3072             // block survivor cap (mean ~400)

// ---------------------------------------------------------------------------
// Single fused kernel (R6 -- best measured at 28.27 us). Block b owns tiles
// (txb..txb+3, ty), ty = b & 31.
//  1a) conservative sqrt-free prefilter: for PSD cov, lam_max <= trace, so
//      r <= 3*sqrt(trace). Reject if band-distance^2 > 9.2*trace (2% slack
//      makes it strictly conservative vs any fma/rounding drift). Survivors
//      ballot-compacted into LDS (order nondeterministic -- fixed by sort).
//  1b) exact _rn radius chain + exact y/x overlap tests on survivors only
//      (dense, all lanes active). Byte-identical selection arithmetic.
//  2)  per-tile stable depth sort: rank sort over unique 64-bit keys
//      (depth_bits << 32) | idx  (depth >= 0 -> bits order-isomorphic).
//  3)  gather first min(M,64) params (precompute 1/det), blend, store.
// ---------------------------------------------------------------------------
__global__ __launch_bounds__(BT) void fused_splat(
    const float* __restrict__ pos2d, const float* __restrict__ cov2d,
    const float* __restrict__ opac,  const float* __restrict__ color,
    const float* __restrict__ depth, float* __restrict__ out, int N)
{
    __shared__ int      s_scnt;
    __shared__ int      s_surv[SURVCAP];
    __shared__ int      s_cnt[TPB];
    __shared__ int      s_cand[TPB][CCAP];
    __shared__ uint64_t s_keys[TPB][CCAP];
    __shared__ int      s_sel[TPB][KMAX];
    __shared__ float4   pA[TPB][KMAX], pB[TPB][KMAX], pC[TPB][KMAX];

    const int t    = threadIdx.x;
    const int lane = t & 63;
    const int ty   = blockIdx.x & (TYN - 1);
    const int txb  = (blockIdx.x >> 5) * TPB;
    const float Tf  = (float)(ty * TILE_LEN);
    const float Lf0 = (float)(txb * TILE_LEN);
    const float Yc  = Tf + 8.0f;     // row band center
    const float Xc  = Lf0 + 32.0f;   // 4-tile band center

    if (t == 0) s_scnt = 0;
    if (t < TPB) s_cnt[t] = 0;
    __syncthreads();

    // ---- Phase 1a: conservative band prefilter + ballot compaction
#pragma unroll 2
    for (int base = 0; base < N; base += BT) {
        const int i = base + t;
        bool sv = false;
        if (i < N) {
            const float2 p  = ((const float2*)pos2d)[i];
            const float4 cv = ((const float4*)cov2d)[i];   // [a, b, b, c]
            const float rb2 = 9.2f * (cv.x + cv.w);        // (3*sqrt(trace))^2 * slack
            const float sy = fabsf(p.y - Yc) - 8.0f;
            const float sx = fabsf(p.x - Xc) - 32.0f;
            const bool rejY = (sy > 0.0f) && (sy * sy > rb2);
            const bool rejX = (sx > 0.0f) && (sx * sx > rb2);
            sv = !(rejY || rejX);
        }
        const unsigned long long msk = __ballot(sv);
        int wbase = 0;
        if (lane == 0 && msk) wbase = atomicAdd(&s_scnt, __popcll(msk));
        wbase = __shfl(wbase, 0);
        if (sv) {
            const int pos = wbase + __popcll(msk & ((1ull << lane) - 1ull));
            if (pos < SURVCAP) s_surv[pos] = i;
        }
    }
    __syncthreads();
    const int S = min(s_scnt, SURVCAP);

    // ---- Phase 1b: exact selection tests on survivors (dense)
    for (int k = t; k < S; k += BT) {
        const int i = s_surv[k];
        const float2 p  = ((const float2*)pos2d)[i];
        const float4 cv = ((const float4*)cov2d)[i];
        const float a = cv.x, b = cv.y, c = cv.w;

        // radius chain with _rn intrinsics: forbids fma contraction
        // (selection-critical, feeds exact bbox-overlap compares)
        const float trace = __fadd_rn(a, c);
        const float det   = __fsub_rn(__fmul_rn(a, c), __fmul_rn(b, b));
        float arg = __fsub_rn(__fmul_rn(trace, trace), __fmul_rn(4.0f, det));
        arg = fmaxf(arg, 0.0f);
        const float t1 = __fmul_rn(0.5f, trace);
        const float t2 = __fmul_rn(0.5f, sqrtf(arg));
        const float lam = fmaxf(__fsub_rn(t1, t2), __fadd_rn(t1, t2));
        const float r = __fmul_rn(3.0f, sqrtf(lam));

        const float yp = __fadd_rn(p.y, r);
        const float ym = __fsub_rn(p.y, r);
        if ((yp > Tf) && (ym < Tf + (float)TILE_LEN)) {
            const float xp = __fadd_rn(p.x, r);
            const float xm = __fsub_rn(p.x, r);
#pragma unroll
            for (int g = 0; g < TPB; ++g) {
                const float Lf = Lf0 + (float)(g * TILE_LEN);
                if ((xp > Lf) && (xm < Lf + (float)TILE_LEN)) {
                    const int pos = atomicAdd(&s_cnt[g], 1);   // LDS atomic
                    if (pos < CCAP) s_cand[g][pos] = i;
                }
            }
        }
    }
    __syncthreads();

    // ---- Phase 2: per-tile stable depth sort (rank sort, unique keys)
    const int g8 = t >> 8;    // tile group 0..3 (256 threads each)
    const int m  = t & 255;
    const int M  = min(s_cnt[g8], CCAP);

    uint64_t mykey = 0;
    int myidx = -1;
    if (m < M) {
        myidx = s_cand[g8][m];
        mykey = ((uint64_t)__float_as_uint(depth[myidx]) << 32) | (uint32_t)myidx;
        s_keys[g8][m] = mykey;
    }
    __syncthreads();

    if (m < M) {
        int rank = 0;
        for (int j = 0; j < M; ++j)
            rank += (s_keys[g8][j] < mykey) ? 1 : 0;
        if (rank < KMAX) s_sel[g8][rank] = myidx;   // unique ranks
    }
    __syncthreads();

    // ---- Phase 3a: gather selected gaussians' params into LDS
    if (t < TPB * KMAX) {
        const int g = t >> 6, k = t & 63;
        const int K = min(min(s_cnt[g], CCAP), KMAX);
        if (k < K) {
            const int idx = s_sel[g][k];
            const float2 p  = ((const float2*)pos2d)[idx];
            const float4 cv = ((const float4*)cov2d)[idx];
            const float det = __fsub_rn(__fmul_rn(cv.x, cv.w), __fmul_rn(cv.y, cv.y));
            pA[g][k] = make_float4(p.x, p.y, 0.0f, opac[idx]);
            pB[g][k] = make_float4(cv.x, cv.y, cv.w, 1.0f / det);
            pC[g][k] = make_float4(color[3 * idx], color[3 * idx + 1],
                                   color[3 * idx + 2], 0.0f);
        }
    }
    __syncthreads();

    // ---- Phase 3b: per-pixel front-to-back blend (all 1024 threads)
    const int pix = t & 255;
    const int pi = pix >> 4;       // x offset in tile
    const int pj = pix & 15;       // y offset in tile
    const int K = min(M, KMAX);
    const float x = Lf0 + (float)(g8 * TILE_LEN + pi);
    const float y = Tf + (float)pj;

    float Tacc = 1.0f, cr = 0.0f, cg = 0.0f, cb = 0.0f;
    for (int k = 0; k < K; ++k) {
        const float4 A  = pA[g8][k];
        const float4 B  = pB[g8][k];
        const float4 Cc = pC[g8][k];
        const float dx = x - A.x;
        const float dy = y - A.y;
        const float quad = (B.z * dx * dx - 2.0f * B.y * dx * dy + B.x * dy * dy) * B.w;
        const float prob = __expf(-0.5f * quad);
        const float alpha = fminf(fmaxf(A.w * prob, 0.01f), 0.99f);
        const float wgt = alpha * Tacc;
        cr = fmaf(wgt, Cc.x, cr);
        cg = fmaf(wgt, Cc.y, cg);
        cb = fmaf(wgt, Cc.z, cb);
        Tacc *= (1.0f - alpha);
    }

    const int X = (txb + g8) * TILE_LEN + pi;
    const int Y = ty * TILE_LEN + pj;
    float* o = out + ((size_t)X * IMGW + (size_t)Y) * 3;
    o[0] = cr;
    o[1] = cg;
    o[2] = cb;
}

// ---------------------------------------------------------------------------
extern "C" void kernel_launch(void* const* d_in, const int* in_sizes, int n_in,
                              void* d_out, int out_size, void* d_ws, size_t ws_size,
                              hipStream_t stream)
{
    const float* pos2d = (const float*)d_in[0];
    const float* cov2d = (const float*)d_in[1];
    const float* opac  = (const float*)d_in[2];
    const float* color = (const float*)d_in[3];
    const float* depth = (const float*)d_in[4];
    float* out = (float*)d_out;

    const int N = in_sizes[2];  // opacity count == N_GAUSS

    fused_splat<<<NBLK, BT, 0, stream>>>(pos2d, cov2d, opac, color, depth, out, N);
}